// Round 2
// baseline (254.629 us; speedup 1.0000x reference)
//
#include <hip/hip_runtime.h>
#include <stdint.h>

#define NROWS 65536
#define HD 1024
#define KTILES 32   // K split into 32 tiles of 32

typedef __attribute__((ext_vector_type(8))) short bf16x8;   // 8 bf16 in 4 VGPRs
typedef __attribute__((ext_vector_type(16))) float f32x16;  // MFMA 32x32 accumulator

typedef __attribute__((address_space(1))) const unsigned int* gas_ptr;
typedef __attribute__((address_space(3))) unsigned int* las_ptr;

__device__ __forceinline__ unsigned short f2bf(float f) {
  union { float f; uint32_t u; } v; v.f = f;
  uint32_t u = v.u;
  return (unsigned short)((u + 0x7fffu + ((u >> 16) & 1u)) >> 16);  // RNE
}

__device__ __forceinline__ void gl16(const void* g, void* l) {
  __builtin_amdgcn_global_load_lds((gas_ptr)g, (las_ptr)l, 16, 0, 0);
}

// ---------------- prep: W2 fp32 -> bf16, swizzled granules ----------------
// layout: W2bf[c][k]; 16B granule g stored at position (g&~3) | ((g&3) ^ ((c>>1)&3)).
// This matches the GEMM's LDS layout (64B rows, 4 granules) so staging is linear.
__global__ void k_w2bf(const float* __restrict__ W2, unsigned short* __restrict__ W2bf) {
  int i = blockIdx.x * 256 + threadIdx.x;   // 131072 threads, 1 granule each
  int c = i >> 7, g = i & 127;
  const float4* s4 = (const float4*)(W2 + (size_t)c * HD + g * 8);
  float4 a = s4[0], b = s4[1];
  uint4 pk;
  pk.x = (uint32_t)f2bf(a.x) | ((uint32_t)f2bf(a.y) << 16);
  pk.y = (uint32_t)f2bf(a.z) | ((uint32_t)f2bf(a.w) << 16);
  pk.z = (uint32_t)f2bf(b.x) | ((uint32_t)f2bf(b.y) << 16);
  pk.w = (uint32_t)f2bf(b.z) | ((uint32_t)f2bf(b.w) << 16);
  int gs = (g & 124) | ((g & 3) ^ ((c >> 1) & 3));
  *(uint4*)(W2bf + (size_t)c * HD + gs * 8) = pk;
}

// ---------------- layer 1: h = relu(delta*W1 + b1 + (phi*oh)@Wmeta + oh@bmeta) ----------------
// h bf16 [65536][1024], same granule swizzle as W2bf ((g&3) ^ (row>>1)&3).
__global__ __launch_bounds__(512) void k_layer1(
    const float* __restrict__ x, const float* __restrict__ W1,
    const float* __restrict__ b1, const float* __restrict__ Wmeta,
    const float* __restrict__ bmeta, unsigned short* __restrict__ h) {
  __shared__ float xs[128 * 12];
  int r0 = blockIdx.x * 128;
  int t = threadIdx.x;
  int j0 = t * 2;  // this thread owns output cols j0, j0+1 for 128 rows
  float w1a = W1[j0], w1b = W1[j0 + 1];
  float b1a = b1[j0], b1b = b1[j0 + 1];
  float wma[10], wmb[10], bma[10], bmb[10];
#pragma unroll
  for (int e = 0; e < 10; e++) {
    float2 wmv = *(const float2*)(Wmeta + e * HD + j0);
    float2 bmv = *(const float2*)(bmeta + e * HD + j0);
    wma[e] = wmv.x; wmb[e] = wmv.y; bma[e] = bmv.x; bmb[e] = bmv.y;
  }
  for (int i = t; i < 128 * 12; i += 512) xs[i] = x[(size_t)r0 * 12 + i];
  __syncthreads();
  int g = j0 >> 3;
  for (int r = 0; r < 128; r++) {
    const float* xr = xs + r * 12;
    float delta = xr[10], phi = xr[11];
    float s1a = 0.f, s1b = 0.f, s2a = 0.f, s2b = 0.f;
#pragma unroll
    for (int e = 0; e < 10; e++) {
      float oh = xr[e];
      s1a = fmaf(oh, wma[e], s1a);
      s1b = fmaf(oh, wmb[e], s1b);
      s2a = fmaf(oh, bma[e], s2a);
      s2b = fmaf(oh, bmb[e], s2b);
    }
    float pa = fmaf(delta, w1a, b1a) + fmaf(phi, s1a, s2a);
    float pb = fmaf(delta, w1b, b1b) + fmaf(phi, s1b, s2b);
    pa = fmaxf(pa, 0.f); pb = fmaxf(pb, 0.f);
    uint32_t pk = (uint32_t)f2bf(pa) | ((uint32_t)f2bf(pb) << 16);
    int rr = r0 + r;
    int gs = (g & 124) | ((g & 3) ^ ((rr >> 1) & 3));
    *(uint32_t*)(h + (size_t)rr * HD + gs * 8 + (j0 & 7)) = pk;
  }
}

// ---------------- layers 2+3: 256x256 tile of h@W2^T, phase-pipelined, fused relu+b2, x W3 ----------------
// grid: 1024 blocks = 256 row-tiles x 4 col-tiles; 512 threads = 8 waves (2 wm x 4 wn),
// wave tile 128x64 as 4x2 of 32x32x16 bf16 MFMA.
// LDS: 4 slots x (A[256][32] + B[256][32]) bf16 = 4 x 32 KiB = 128 KiB.
// Pipeline: prefetch distance 3 tiles; per phase {6 ds_read | 2 global_load_lds |
// counted vmcnt(8) | barrier | lgkmcnt(0) | setprio(1) 8xMFMA setprio(0) | barrier}.
__global__ __launch_bounds__(512, 2) void k_gemm(
    const unsigned short* __restrict__ h, const unsigned short* __restrict__ W2bf,
    const float* __restrict__ b2, const float* __restrict__ W3,
    float* __restrict__ partial) {
  extern __shared__ char lds[];
  int tid = threadIdx.x;
  int bx = blockIdx.x;
  int rt = bx >> 2, ct = bx & 3;
  size_t r0 = (size_t)rt * 256;
  int c0 = ct * 256;
  int w = tid >> 6, lane = tid & 63;
  int wm = w >> 2, wn = w & 3;
  int l31 = lane & 31, hi = lane >> 5;

  f32x16 acc[4][2];
#pragma unroll
  for (int rb = 0; rb < 4; rb++)
#pragma unroll
    for (int cb = 0; cb < 2; cb++)
#pragma unroll
      for (int i = 0; i < 16; i++) acc[rb][cb][i] = 0.f;

  // stage part q (0/1) of tile T into slot T&3: 1 A-seg + 1 B-seg per thread.
  // A tile = 256 rows x 64B = 1024 16B-segments, linear in LDS (lane-linear dest),
  // source pre-swizzled so LDS slot j of row r holds logical granule j ^ ((r>>1)&3).
  auto stage1 = [&](int T, int q) {
    int slot = T & 3;
    char* base = lds + (size_t)slot * 32768;
    int s = tid + 512 * q;
    int row = s >> 2, off8 = (s & 3) * 8;
    gl16(h    + (r0 + row) * (size_t)HD + T * 32 + off8, base + (size_t)s * 16);
    gl16(W2bf + (size_t)(c0 + row) * HD + T * 32 + off8, base + 16384 + (size_t)s * 16);
  };

  // prologue: stage tiles 0,1,2 (12 loads/thread); wait until tile 0 landed (<=8 left).
  stage1(0, 0); stage1(0, 1);
  stage1(1, 0); stage1(1, 1);
  stage1(2, 0); stage1(2, 1);
  asm volatile("s_waitcnt vmcnt(8)" ::: "memory");
  __builtin_amdgcn_s_barrier();

  for (int T = 0; T < KTILES; T++) {
    const char* lA = lds + (size_t)(T & 3) * 32768;
    const char* lB = lA + 16384;
#pragma unroll
    for (int p = 0; p < 2; p++) {
      // 1) ds_read this phase's fragments (issued before barrier, waited after)
      int g = p * 2 + hi;  // logical granule 0..3 within the 32-k tile
      bf16x8 av[4], bv[2];
#pragma unroll
      for (int rb = 0; rb < 4; rb++) {
        int row = wm * 128 + rb * 32 + l31;
        av[rb] = *(const bf16x8*)(lA + row * 64 + ((g ^ ((row >> 1) & 3)) << 4));
      }
#pragma unroll
      for (int cb = 0; cb < 2; cb++) {
        int crow = wn * 64 + cb * 32 + l31;
        bv[cb] = *(const bf16x8*)(lB + crow * 64 + ((g ^ ((crow >> 1) & 3)) << 4));
      }
      // 2) issue prefetch of tile T+3 (2 loads per phase)
      if (T < KTILES - 3) stage1(T + 3, p);
      // 3) once per tile: counted vmcnt — tiles T+2,T+3 may stay in flight (8 loads)
      if (p == 1) asm volatile("s_waitcnt vmcnt(8)" ::: "memory");
      asm volatile("" ::: "memory");
      __builtin_amdgcn_s_barrier();
      asm volatile("s_waitcnt lgkmcnt(0)" ::: "memory");
      __builtin_amdgcn_sched_barrier(0);
      // 4) MFMA cluster
      __builtin_amdgcn_s_setprio(1);
#pragma unroll
      for (int rb = 0; rb < 4; rb++)
#pragma unroll
        for (int cb = 0; cb < 2; cb++)
          acc[rb][cb] = __builtin_amdgcn_mfma_f32_32x32x16_bf16(av[rb], bv[cb], acc[rb][cb], 0, 0, 0);
      __builtin_amdgcn_s_setprio(0);
      asm volatile("" ::: "memory");
      __builtin_amdgcn_s_barrier();
    }
  }

  // epilogue: v = relu(acc + b2[c]); out_d += v * W3[d][c]; reduce 32 lanes -> per-row pair.
  float b2c[2], w30[2], w31[2];
#pragma unroll
  for (int cb = 0; cb < 2; cb++) {
    int c = c0 + wn * 64 + cb * 32 + l31;
    b2c[cb] = b2[c];
    w30[cb] = W3[c];
    w31[cb] = W3[HD + c];
  }
  float* sOutW = (float*)lds;  // [4 wn][256 rows][2]
#pragma unroll
  for (int rb = 0; rb < 4; rb++) {
#pragma unroll
    for (int reg = 0; reg < 16; reg++) {
      float v0 = fmaxf(acc[rb][0][reg] + b2c[0], 0.f);
      float v1 = fmaxf(acc[rb][1][reg] + b2c[1], 0.f);
      float o0 = v0 * w30[0] + v1 * w30[1];
      float o1 = v0 * w31[0] + v1 * w31[1];
#pragma unroll
      for (int m = 16; m >= 1; m >>= 1) {  // masks <32: stays within each 32-lane half
        o0 += __shfl_xor(o0, m);
        o1 += __shfl_xor(o1, m);
      }
      if (l31 == 0) {
        int rowf = (reg & 3) + 8 * (reg >> 2) + 4 * hi;  // verified C/D row map (m74/m101)
        int row = wm * 128 + rb * 32 + rowf;
        sOutW[(wn * 256 + row) * 2 + 0] = o0;
        sOutW[(wn * 256 + row) * 2 + 1] = o1;
      }
    }
  }
  __syncthreads();
  {
    int i = tid;  // 512 threads, 512 values (256 rows x 2)
    float s = sOutW[i] + sOutW[512 + i] + sOutW[1024 + i] + sOutW[1536 + i];
    partial[(size_t)ct * (NROWS * 2) + r0 * 2 + i] = s;
  }
}

// ---------------- final: out = b3 + sum over 4 col-tile partials ----------------
__global__ void k_reduce(const float* __restrict__ partial, const float* __restrict__ b3,
                         float* __restrict__ out) {
  int i = blockIdx.x * 256 + threadIdx.x;  // 131072
  float s = b3[i & 1] + partial[i] + partial[131072 + i] + partial[262144 + i] + partial[393216 + i];
  out[i] = s;
}

extern "C" void kernel_launch(void* const* d_in, const int* in_sizes, int n_in,
                              void* d_out, int out_size, void* d_ws, size_t ws_size,
                              hipStream_t stream) {
  const float* x     = (const float*)d_in[0];
  const float* W1    = (const float*)d_in[1];
  const float* b1    = (const float*)d_in[2];
  const float* Wmeta = (const float*)d_in[3];
  const float* bmeta = (const float*)d_in[4];
  const float* W2    = (const float*)d_in[5];
  const float* b2    = (const float*)d_in[6];
  const float* W3    = (const float*)d_in[7];
  const float* b3    = (const float*)d_in[8];
  float* out = (float*)d_out;

  char* ws = (char*)d_ws;
  unsigned short* hbuf  = (unsigned short*)ws;                              // 128 MiB
  unsigned short* W2bf  = (unsigned short*)(ws + (size_t)NROWS * HD * 2);   // 2 MiB
  float* partial = (float*)(ws + (size_t)NROWS * HD * 2 + (size_t)HD * HD * 2);  // 2 MiB

  hipFuncSetAttribute((const void*)k_gemm, hipFuncAttributeMaxDynamicSharedMemorySize, 131072);

  k_w2bf<<<512, 256, 0, stream>>>(W2, W2bf);
  k_layer1<<<512, 512, 0, stream>>>(x, W1, b1, Wmeta, bmeta, hbuf);
  k_gemm<<<1024, 512, 131072, stream>>>(hbuf, W2bf, b2, W3, partial);
  k_reduce<<<512, 256, 0, stream>>>(partial, b3, out);
}

// Round 3
// 247.843 us; speedup vs baseline: 1.0274x; 1.0274x over previous
//
#include <hip/hip_runtime.h>
#include <stdint.h>

#define NROWS 65536
#define HD 1024
#define KTILES 32   // K split into 32 tiles of 32

typedef __attribute__((ext_vector_type(8))) short bf16x8;   // 8 bf16 in 4 VGPRs
typedef __attribute__((ext_vector_type(16))) float f32x16;  // MFMA 32x32 accumulator

typedef __attribute__((address_space(1))) const unsigned int* gas_ptr;
typedef __attribute__((address_space(3))) unsigned int* las_ptr;

__device__ __forceinline__ unsigned short f2bf(float f) {
  union { float f; uint32_t u; } v; v.f = f;
  uint32_t u = v.u;
  return (unsigned short)((u + 0x7fffu + ((u >> 16) & 1u)) >> 16);  // RNE
}

__device__ __forceinline__ void gl16(const void* g, void* l) {
  __builtin_amdgcn_global_load_lds((gas_ptr)g, (las_ptr)l, 16, 0, 0);
}

// ---------------- prep: W2 fp32 -> bf16, swizzled granules ----------------
// layout: W2bf[c][k]; 16B granule g stored at position (g&~3) | ((g&3) ^ ((c>>1)&3)).
__global__ void k_w2bf(const float* __restrict__ W2, unsigned short* __restrict__ W2bf) {
  int i = blockIdx.x * 256 + threadIdx.x;   // 131072 threads, 1 granule each
  int c = i >> 7, g = i & 127;
  const float4* s4 = (const float4*)(W2 + (size_t)c * HD + g * 8);
  float4 a = s4[0], b = s4[1];
  uint4 pk;
  pk.x = (uint32_t)f2bf(a.x) | ((uint32_t)f2bf(a.y) << 16);
  pk.y = (uint32_t)f2bf(a.z) | ((uint32_t)f2bf(a.w) << 16);
  pk.z = (uint32_t)f2bf(b.x) | ((uint32_t)f2bf(b.y) << 16);
  pk.w = (uint32_t)f2bf(b.z) | ((uint32_t)f2bf(b.w) << 16);
  int gs = (g & 124) | ((g & 3) ^ ((c >> 1) & 3));
  *(uint4*)(W2bf + (size_t)c * HD + gs * 8) = pk;
}

// ---------------- layer 1: h = relu(delta*W1 + b1 + (phi*oh)@Wmeta + oh@bmeta) ----------------
// h bf16 [65536][1024], same granule swizzle as W2bf ((g&3) ^ (row>>1)&3).
__global__ __launch_bounds__(512) void k_layer1(
    const float* __restrict__ x, const float* __restrict__ W1,
    const float* __restrict__ b1, const float* __restrict__ Wmeta,
    const float* __restrict__ bmeta, unsigned short* __restrict__ h) {
  __shared__ float xs[128 * 12];
  int r0 = blockIdx.x * 128;
  int t = threadIdx.x;
  int j0 = t * 2;  // this thread owns output cols j0, j0+1 for 128 rows
  float w1a = W1[j0], w1b = W1[j0 + 1];
  float b1a = b1[j0], b1b = b1[j0 + 1];
  float wma[10], wmb[10], bma[10], bmb[10];
#pragma unroll
  for (int e = 0; e < 10; e++) {
    float2 wmv = *(const float2*)(Wmeta + e * HD + j0);
    float2 bmv = *(const float2*)(bmeta + e * HD + j0);
    wma[e] = wmv.x; wmb[e] = wmv.y; bma[e] = bmv.x; bmb[e] = bmv.y;
  }
  for (int i = t; i < 128 * 12; i += 512) xs[i] = x[(size_t)r0 * 12 + i];
  __syncthreads();
  int g = j0 >> 3;
  for (int r = 0; r < 128; r++) {
    const float* xr = xs + r * 12;
    float delta = xr[10], phi = xr[11];
    float s1a = 0.f, s1b = 0.f, s2a = 0.f, s2b = 0.f;
#pragma unroll
    for (int e = 0; e < 10; e++) {
      float oh = xr[e];
      s1a = fmaf(oh, wma[e], s1a);
      s1b = fmaf(oh, wmb[e], s1b);
      s2a = fmaf(oh, bma[e], s2a);
      s2b = fmaf(oh, bmb[e], s2b);
    }
    float pa = fmaf(delta, w1a, b1a) + fmaf(phi, s1a, s2a);
    float pb = fmaf(delta, w1b, b1b) + fmaf(phi, s1b, s2b);
    pa = fmaxf(pa, 0.f); pb = fmaxf(pb, 0.f);
    uint32_t pk = (uint32_t)f2bf(pa) | ((uint32_t)f2bf(pb) << 16);
    int rr = r0 + r;
    int gs = (g & 124) | ((g & 3) ^ ((rr >> 1) & 3));
    *(uint32_t*)(h + (size_t)rr * HD + gs * 8 + (j0 & 7)) = pk;
  }
}

// ---------------- layers 2+3: 256x256 tile, single-barrier counted-vmcnt pipeline ----------------
// grid: 1024 blocks (XCD-swizzled) = 256 row-tiles x 4 col-tiles; 512 threads = 8 waves (2x4),
// wave tile 128x64 as 4x2 of 32x32x16 bf16 MFMA.
// LDS: 4 slots x (A[256][32] + B[256][32]) bf16 = 128 KiB. Prefetch distance 3 tiles.
// Per K-tile (one phase): {12 ds_read | stage t+3 (4 gl_lds) | lgkmcnt(0) |
//   setprio(1) 16 MFMA setprio(0) | vmcnt(8) | s_barrier}.
// vmcnt(8): tiles t+2,t+3 stay in flight; guards tile t+1 which is read after the barrier.
// Slot safety: slot(t+3)=slot(t-1); all phase-(t-1) ds_reads retired before barrier E(t-1).
__global__ __launch_bounds__(512, 2) void k_gemm(
    const unsigned short* __restrict__ h, const unsigned short* __restrict__ W2bf,
    const float* __restrict__ b2, const float* __restrict__ W3,
    float* __restrict__ partial) {
  extern __shared__ char lds[];
  int tid = threadIdx.x;
  // XCD-aware swizzle: 1024 blocks, 8 XCDs -> XCD k owns logical tiles [k*128, k*128+128).
  int bx = ((blockIdx.x & 7) << 7) | (blockIdx.x >> 3);
  int rt = bx >> 2, ct = bx & 3;
  size_t r0 = (size_t)rt * 256;
  int c0 = ct * 256;
  int w = tid >> 6, lane = tid & 63;
  int wm = w >> 2, wn = w & 3;
  int l31 = lane & 31, hi = lane >> 5;

  f32x16 acc[4][2];
#pragma unroll
  for (int rb = 0; rb < 4; rb++)
#pragma unroll
    for (int cb = 0; cb < 2; cb++)
#pragma unroll
      for (int i = 0; i < 16; i++) acc[rb][cb][i] = 0.f;

  // stage tile T into slot T&3: 2 A-segs + 2 B-segs per thread (4 gl_lds).
  auto stage = [&](int T) {
    int slot = T & 3;
    char* base = lds + (size_t)slot * 32768;
#pragma unroll
    for (int q = 0; q < 2; q++) {
      int s = tid + 512 * q;          // 1024 16B segments per matrix
      int row = s >> 2, off8 = (s & 3) * 8;
      gl16(h    + (r0 + row) * (size_t)HD + T * 32 + off8, base + (size_t)s * 16);
      gl16(W2bf + (size_t)(c0 + row) * HD + T * 32 + off8, base + 16384 + (size_t)s * 16);
    }
  };

  // prologue: stage tiles 0,1,2 (12 loads/thread); wait tile 0 (<=8 outstanding); barrier.
  stage(0); stage(1); stage(2);
  asm volatile("s_waitcnt vmcnt(8)" ::: "memory");
  __builtin_amdgcn_s_barrier();

  for (int T = 0; T < KTILES; T++) {
    const char* lA = lds + (size_t)(T & 3) * 32768;
    const char* lB = lA + 16384;
    // 1) ds_read all 12 fragments of this tile
    bf16x8 av[2][4], bv[2][2];
#pragma unroll
    for (int kk = 0; kk < 2; kk++) {
      int g = kk * 2 + hi;  // logical granule 0..3 within the 32-k tile
#pragma unroll
      for (int rb = 0; rb < 4; rb++) {
        int row = wm * 128 + rb * 32 + l31;
        av[kk][rb] = *(const bf16x8*)(lA + row * 64 + ((g ^ ((row >> 1) & 3)) << 4));
      }
#pragma unroll
      for (int cb = 0; cb < 2; cb++) {
        int crow = wn * 64 + cb * 32 + l31;
        bv[kk][cb] = *(const bf16x8*)(lB + crow * 64 + ((g ^ ((crow >> 1) & 3)) << 4));
      }
    }
    // 2) issue prefetch of tile T+3 into slot (T-1)&3 (safe: those reads retired)
    if (T < KTILES - 3) stage(T + 3);
    // 3) wait own ds_reads, fence the machine scheduler (rule 18)
    asm volatile("s_waitcnt lgkmcnt(0)" ::: "memory");
    __builtin_amdgcn_sched_barrier(0);
    // 4) MFMA cluster (16)
    __builtin_amdgcn_s_setprio(1);
#pragma unroll
    for (int kk = 0; kk < 2; kk++)
#pragma unroll
      for (int rb = 0; rb < 4; rb++)
#pragma unroll
        for (int cb = 0; cb < 2; cb++)
          acc[rb][cb] = __builtin_amdgcn_mfma_f32_32x32x16_bf16(av[kk][rb], bv[kk][cb], acc[rb][cb], 0, 0, 0);
    __builtin_amdgcn_s_setprio(0);
    // 5) counted vmcnt AFTER compute: tile T+1 must be landed before the barrier releases
    asm volatile("s_waitcnt vmcnt(8)" ::: "memory");
    __builtin_amdgcn_s_barrier();
  }

  // epilogue: v = relu(acc + b2[c]); out_d += v * W3[d][c]; reduce 32 lanes -> per-row pair.
  float b2c[2], w30[2], w31[2];
#pragma unroll
  for (int cb = 0; cb < 2; cb++) {
    int c = c0 + wn * 64 + cb * 32 + l31;
    b2c[cb] = b2[c];
    w30[cb] = W3[c];
    w31[cb] = W3[HD + c];
  }
  float* sOutW = (float*)lds;  // [4 wn][256 rows][2]
#pragma unroll
  for (int rb = 0; rb < 4; rb++) {
#pragma unroll
    for (int reg = 0; reg < 16; reg++) {
      float v0 = fmaxf(acc[rb][0][reg] + b2c[0], 0.f);
      float v1 = fmaxf(acc[rb][1][reg] + b2c[1], 0.f);
      float o0 = v0 * w30[0] + v1 * w30[1];
      float o1 = v0 * w31[0] + v1 * w31[1];
#pragma unroll
      for (int m = 16; m >= 1; m >>= 1) {  // masks <32: stays within each 32-lane half
        o0 += __shfl_xor(o0, m);
        o1 += __shfl_xor(o1, m);
      }
      if (l31 == 0) {
        int rowf = (reg & 3) + 8 * (reg >> 2) + 4 * hi;  // verified C/D row map (m74/m101)
        int row = wm * 128 + rb * 32 + rowf;
        sOutW[(wn * 256 + row) * 2 + 0] = o0;
        sOutW[(wn * 256 + row) * 2 + 1] = o1;
      }
    }
  }
  __syncthreads();
  {
    int i = tid;  // 512 threads, 512 values (256 rows x 2)
    float s = sOutW[i] + sOutW[512 + i] + sOutW[1024 + i] + sOutW[1536 + i];
    partial[(size_t)ct * (NROWS * 2) + r0 * 2 + i] = s;
  }
}

// ---------------- final: out = b3 + sum over 4 col-tile partials ----------------
__global__ void k_reduce(const float* __restrict__ partial, const float* __restrict__ b3,
                         float* __restrict__ out) {
  int i = blockIdx.x * 256 + threadIdx.x;  // 131072
  float s = b3[i & 1] + partial[i] + partial[131072 + i] + partial[262144 + i] + partial[393216 + i];
  out[i] = s;
}

extern "C" void kernel_launch(void* const* d_in, const int* in_sizes, int n_in,
                              void* d_out, int out_size, void* d_ws, size_t ws_size,
                              hipStream_t stream) {
  const float* x     = (const float*)d_in[0];
  const float* W1    = (const float*)d_in[1];
  const float* b1    = (const float*)d_in[2];
  const float* Wmeta = (const float*)d_in[3];
  const float* bmeta = (const float*)d_in[4];
  const float* W2    = (const float*)d_in[5];
  const float* b2    = (const float*)d_in[6];
  const float* W3    = (const float*)d_in[7];
  const float* b3    = (const float*)d_in[8];
  float* out = (float*)d_out;

  char* ws = (char*)d_ws;
  unsigned short* hbuf  = (unsigned short*)ws;                              // 128 MiB
  unsigned short* W2bf  = (unsigned short*)(ws + (size_t)NROWS * HD * 2);   // 2 MiB
  float* partial = (float*)(ws + (size_t)NROWS * HD * 2 + (size_t)HD * HD * 2);  // 2 MiB

  hipFuncSetAttribute((const void*)k_gemm, hipFuncAttributeMaxDynamicSharedMemorySize, 131072);

  k_w2bf<<<512, 256, 0, stream>>>(W2, W2bf);
  k_layer1<<<512, 512, 0, stream>>>(x, W1, b1, Wmeta, bmeta, hbuf);
  k_gemm<<<1024, 512, 131072, stream>>>(hbuf, W2bf, b2, W3, partial);
  k_reduce<<<512, 256, 0, stream>>>(partial, b3, out);
}

// Round 4
// 241.849 us; speedup vs baseline: 1.0528x; 1.0248x over previous
//
#include <hip/hip_runtime.h>
#include <stdint.h>

#define NROWS 65536
#define HD 1024
#define KTILES 32   // K split into 32 tiles of 32

typedef __attribute__((ext_vector_type(8))) short bf16x8;   // 8 bf16 in 4 VGPRs
typedef __attribute__((ext_vector_type(16))) float f32x16;  // MFMA 32x32 accumulator

typedef __attribute__((address_space(1))) const unsigned int* gas_ptr;
typedef __attribute__((address_space(3))) unsigned int* las_ptr;

__device__ __forceinline__ unsigned short f2bf(float f) {
  union { float f; uint32_t u; } v; v.f = f;
  uint32_t u = v.u;
  return (unsigned short)((u + 0x7fffu + ((u >> 16) & 1u)) >> 16);  // RNE
}

__device__ __forceinline__ void gl16(const void* g, void* l) {
  __builtin_amdgcn_global_load_lds((gas_ptr)g, (las_ptr)l, 16, 0, 0);
}

// ---------------- prep: W2 fp32 -> bf16, swizzled granules ----------------
// layout: W2bf[c][k]; 16B granule g stored at position (g&~3) | ((g&3) ^ ((c>>1)&3)).
__global__ void k_w2bf(const float* __restrict__ W2, unsigned short* __restrict__ W2bf) {
  int i = blockIdx.x * 256 + threadIdx.x;   // 131072 threads, 1 granule each
  int c = i >> 7, g = i & 127;
  const float4* s4 = (const float4*)(W2 + (size_t)c * HD + g * 8);
  float4 a = s4[0], b = s4[1];
  uint4 pk;
  pk.x = (uint32_t)f2bf(a.x) | ((uint32_t)f2bf(a.y) << 16);
  pk.y = (uint32_t)f2bf(a.z) | ((uint32_t)f2bf(a.w) << 16);
  pk.z = (uint32_t)f2bf(b.x) | ((uint32_t)f2bf(b.y) << 16);
  pk.w = (uint32_t)f2bf(b.z) | ((uint32_t)f2bf(b.w) << 16);
  int gs = (g & 124) | ((g & 3) ^ ((c >> 1) & 3));
  *(uint4*)(W2bf + (size_t)c * HD + gs * 8) = pk;
}

// ---------------- layer 1: h = relu(delta*W1 + b1 + (phi*oh)@Wmeta + oh@bmeta) ----------------
// h bf16 [65536][1024], same granule swizzle as W2bf ((g&3) ^ (row>>1)&3).
__global__ __launch_bounds__(512) void k_layer1(
    const float* __restrict__ x, const float* __restrict__ W1,
    const float* __restrict__ b1, const float* __restrict__ Wmeta,
    const float* __restrict__ bmeta, unsigned short* __restrict__ h) {
  __shared__ float xs[128 * 12];
  int r0 = blockIdx.x * 128;
  int t = threadIdx.x;
  int j0 = t * 2;  // this thread owns output cols j0, j0+1 for 128 rows
  float w1a = W1[j0], w1b = W1[j0 + 1];
  float b1a = b1[j0], b1b = b1[j0 + 1];
  float wma[10], wmb[10], bma[10], bmb[10];
#pragma unroll
  for (int e = 0; e < 10; e++) {
    float2 wmv = *(const float2*)(Wmeta + e * HD + j0);
    float2 bmv = *(const float2*)(bmeta + e * HD + j0);
    wma[e] = wmv.x; wmb[e] = wmv.y; bma[e] = bmv.x; bmb[e] = bmv.y;
  }
  for (int i = t; i < 128 * 12; i += 512) xs[i] = x[(size_t)r0 * 12 + i];
  __syncthreads();
  int g = j0 >> 3;
  for (int r = 0; r < 128; r++) {
    const float* xr = xs + r * 12;
    float delta = xr[10], phi = xr[11];
    float s1a = 0.f, s1b = 0.f, s2a = 0.f, s2b = 0.f;
#pragma unroll
    for (int e = 0; e < 10; e++) {
      float oh = xr[e];
      s1a = fmaf(oh, wma[e], s1a);
      s1b = fmaf(oh, wmb[e], s1b);
      s2a = fmaf(oh, bma[e], s2a);
      s2b = fmaf(oh, bmb[e], s2b);
    }
    float pa = fmaf(delta, w1a, b1a) + fmaf(phi, s1a, s2a);
    float pb = fmaf(delta, w1b, b1b) + fmaf(phi, s1b, s2b);
    pa = fmaxf(pa, 0.f); pb = fmaxf(pb, 0.f);
    uint32_t pk = (uint32_t)f2bf(pa) | ((uint32_t)f2bf(pb) << 16);
    int rr = r0 + r;
    int gs = (g & 124) | ((g & 3) ^ ((rr >> 1) & 3));
    *(uint32_t*)(h + (size_t)rr * HD + gs * 8 + (j0 & 7)) = pk;
  }
}

#define MFMA8(A, B)                                                                   \
  do {                                                                                \
    __builtin_amdgcn_s_setprio(1);                                                    \
    acc[0][0] = __builtin_amdgcn_mfma_f32_32x32x16_bf16(A##0, B##0, acc[0][0], 0,0,0);\
    acc[0][1] = __builtin_amdgcn_mfma_f32_32x32x16_bf16(A##0, B##1, acc[0][1], 0,0,0);\
    acc[1][0] = __builtin_amdgcn_mfma_f32_32x32x16_bf16(A##1, B##0, acc[1][0], 0,0,0);\
    acc[1][1] = __builtin_amdgcn_mfma_f32_32x32x16_bf16(A##1, B##1, acc[1][1], 0,0,0);\
    acc[2][0] = __builtin_amdgcn_mfma_f32_32x32x16_bf16(A##2, B##0, acc[2][0], 0,0,0);\
    acc[2][1] = __builtin_amdgcn_mfma_f32_32x32x16_bf16(A##2, B##1, acc[2][1], 0,0,0);\
    acc[3][0] = __builtin_amdgcn_mfma_f32_32x32x16_bf16(A##3, B##0, acc[3][0], 0,0,0);\
    acc[3][1] = __builtin_amdgcn_mfma_f32_32x32x16_bf16(A##3, B##1, acc[3][1], 0,0,0);\
    __builtin_amdgcn_s_setprio(0);                                                    \
  } while (0)

// ---------------- layers 2+3: 256x256 tile, intra-wave pipelined counted-vmcnt loop ----------------
// 1024 blocks (XCD-swizzled) = 256 rt x 4 ct; 512 threads = 8 waves (2x4), wave tile 128x64.
// LDS: 4 slots x (A[256][32]+B[256][32]) bf16 = 128 KiB. Prefetch distance 3, vmcnt(4):
// at barrier E(T), tiles <= T+2 landed. Per tile: {read k1 frags | lgkm(6) | 8 MFMA k0 |
// read (T+1) k0 frags (cross-barrier, landed since E(T-1)) | stage T+3 | lgkm(6) | 8 MFMA k1
// | vmcnt(4) | s_barrier}. Every wave's slot-T reads retire before its E(T) arrival, so
// stage(T+3) into slot (T-1)&3 after E(T-1) is race-free.
__global__ __launch_bounds__(512, 2) void k_gemm(
    const unsigned short* __restrict__ h, const unsigned short* __restrict__ W2bf,
    const float* __restrict__ b2, const float* __restrict__ W3,
    float* __restrict__ partial) {
  extern __shared__ char lds[];
  int tid = threadIdx.x;
  // XCD-aware swizzle: 1024 blocks, 8 XCDs -> XCD k owns logical tiles [k*128, k*128+128).
  int bx = ((blockIdx.x & 7) << 7) | (blockIdx.x >> 3);
  int rt = bx >> 2, ct = bx & 3;
  size_t r0 = (size_t)rt * 256;
  int c0 = ct * 256;
  int w = tid >> 6, lane = tid & 63;
  int wm = w >> 2, wn = w & 3;
  int l31 = lane & 31, hi = lane >> 5;
  int sw = (l31 >> 1) & 3;              // swizzle key, constant per thread
  int aoff = (wm * 128 + l31) * 64;     // + rb*2048 + ((g^sw)<<4)
  int boff = (wn * 64 + l31) * 64;      // + cb*2048 + ((g^sw)<<4)
  int glo = (hi ^ sw) << 4;             // granule offset for g = hi
  int ghi = ((2 + hi) ^ sw) << 4;       // granule offset for g = 2+hi

  f32x16 acc[4][2];
#pragma unroll
  for (int rb = 0; rb < 4; rb++)
#pragma unroll
    for (int cb = 0; cb < 2; cb++)
#pragma unroll
      for (int i = 0; i < 16; i++) acc[rb][cb][i] = 0.f;

  auto stage = [&](int T) {
    char* base = lds + (size_t)(T & 3) * 32768;
#pragma unroll
    for (int q = 0; q < 2; q++) {
      int s = tid + 512 * q;
      int row = s >> 2, off8 = (s & 3) * 8;
      gl16(h    + (r0 + row) * (size_t)HD + T * 32 + off8, base + (size_t)s * 16);
      gl16(W2bf + (size_t)(c0 + row) * HD + T * 32 + off8, base + 16384 + (size_t)s * 16);
    }
  };

  // prologue: stage 0,1,2; tiles 0,1 landed; read tile0 k0 frags.
  stage(0); stage(1); stage(2);
  asm volatile("s_waitcnt vmcnt(4)" ::: "memory");
  __builtin_amdgcn_s_barrier();

  const char* lA = lds;
  const char* lB = lds + 16384;
  bf16x8 a00, a01, a02, a03, b00, b01;   // current k0 frags
  bf16x8 a10, a11, a12, a13, b10, b11;   // current k1 frags
  a00 = *(const bf16x8*)(lA + aoff + 0    + glo);
  a01 = *(const bf16x8*)(lA + aoff + 2048 + glo);
  a02 = *(const bf16x8*)(lA + aoff + 4096 + glo);
  a03 = *(const bf16x8*)(lA + aoff + 6144 + glo);
  b00 = *(const bf16x8*)(lB + boff + 0    + glo);
  b01 = *(const bf16x8*)(lB + boff + 2048 + glo);

  for (int T = 0; T < KTILES - 1; T++) {
    lA = lds + (size_t)(T & 3) * 32768;
    lB = lA + 16384;
    const char* lA1 = lds + (size_t)((T + 1) & 3) * 32768;
    const char* lB1 = lA1 + 16384;
    // issue k1 frags of tile T
    a10 = *(const bf16x8*)(lA + aoff + 0    + ghi);
    a11 = *(const bf16x8*)(lA + aoff + 2048 + ghi);
    a12 = *(const bf16x8*)(lA + aoff + 4096 + ghi);
    a13 = *(const bf16x8*)(lA + aoff + 6144 + ghi);
    b10 = *(const bf16x8*)(lB + boff + 0    + ghi);
    b11 = *(const bf16x8*)(lB + boff + 2048 + ghi);
    asm volatile("s_waitcnt lgkmcnt(6)" ::: "memory");   // k0 frags ready
    __builtin_amdgcn_sched_barrier(0);
    MFMA8(a0, b0);
    // issue k0 frags of tile T+1 (landed since E(T-1); crosses E(T))
    a00 = *(const bf16x8*)(lA1 + aoff + 0    + glo);
    a01 = *(const bf16x8*)(lA1 + aoff + 2048 + glo);
    a02 = *(const bf16x8*)(lA1 + aoff + 4096 + glo);
    a03 = *(const bf16x8*)(lA1 + aoff + 6144 + glo);
    b00 = *(const bf16x8*)(lB1 + boff + 0    + glo);
    b01 = *(const bf16x8*)(lB1 + boff + 2048 + glo);
    if (T < KTILES - 3) stage(T + 3);
    asm volatile("s_waitcnt lgkmcnt(6)" ::: "memory");   // k1 frags ready
    __builtin_amdgcn_sched_barrier(0);
    MFMA8(a1, b1);
    asm volatile("s_waitcnt vmcnt(4)" ::: "memory");     // tile T+2 landed
    __builtin_amdgcn_s_barrier();
  }
  // tail: tile 31
  {
    lA = lds + (size_t)((KTILES - 1) & 3) * 32768;
    lB = lA + 16384;
    a10 = *(const bf16x8*)(lA + aoff + 0    + ghi);
    a11 = *(const bf16x8*)(lA + aoff + 2048 + ghi);
    a12 = *(const bf16x8*)(lA + aoff + 4096 + ghi);
    a13 = *(const bf16x8*)(lA + aoff + 6144 + ghi);
    b10 = *(const bf16x8*)(lB + boff + 0    + ghi);
    b11 = *(const bf16x8*)(lB + boff + 2048 + ghi);
    asm volatile("s_waitcnt lgkmcnt(6)" ::: "memory");
    __builtin_amdgcn_sched_barrier(0);
    MFMA8(a0, b0);
    asm volatile("s_waitcnt lgkmcnt(0)" ::: "memory");   // counted 6 would NOT wait here
    __builtin_amdgcn_sched_barrier(0);
    MFMA8(a1, b1);
  }
  __syncthreads();  // all slot reads done before LDS reuse

  // epilogue: v = relu(acc + b2[c]); out_d += v * W3[d][c]; reduce 32 lanes -> per-row pair.
  float b2c[2], w30[2], w31[2];
#pragma unroll
  for (int cb = 0; cb < 2; cb++) {
    int c = c0 + wn * 64 + cb * 32 + l31;
    b2c[cb] = b2[c];
    w30[cb] = W3[c];
    w31[cb] = W3[HD + c];
  }
  float* sOutW = (float*)lds;  // [4 wn][256 rows][2]
#pragma unroll
  for (int rb = 0; rb < 4; rb++) {
#pragma unroll
    for (int reg = 0; reg < 16; reg++) {
      float v0 = fmaxf(acc[rb][0][reg] + b2c[0], 0.f);
      float v1 = fmaxf(acc[rb][1][reg] + b2c[1], 0.f);
      float o0 = v0 * w30[0] + v1 * w30[1];
      float o1 = v0 * w31[0] + v1 * w31[1];
#pragma unroll
      for (int m = 16; m >= 1; m >>= 1) {  // masks <32: stays within each 32-lane half
        o0 += __shfl_xor(o0, m);
        o1 += __shfl_xor(o1, m);
      }
      if (l31 == 0) {
        int rowf = (reg & 3) + 8 * (reg >> 2) + 4 * hi;  // verified C/D row map (m74/m101)
        int row = wm * 128 + rb * 32 + rowf;
        sOutW[(wn * 256 + row) * 2 + 0] = o0;
        sOutW[(wn * 256 + row) * 2 + 1] = o1;
      }
    }
  }
  __syncthreads();
  {
    int i = tid;  // 512 threads, 512 values (256 rows x 2)
    float s = sOutW[i] + sOutW[512 + i] + sOutW[1024 + i] + sOutW[1536 + i];
    partial[(size_t)ct * (NROWS * 2) + r0 * 2 + i] = s;
  }
}

// ---------------- final: out = b3 + sum over 4 col-tile partials ----------------
__global__ void k_reduce(const float* __restrict__ partial, const float* __restrict__ b3,
                         float* __restrict__ out) {
  int i = blockIdx.x * 256 + threadIdx.x;  // 131072
  float s = b3[i & 1] + partial[i] + partial[131072 + i] + partial[262144 + i] + partial[393216 + i];
  out[i] = s;
}

extern "C" void kernel_launch(void* const* d_in, const int* in_sizes, int n_in,
                              void* d_out, int out_size, void* d_ws, size_t ws_size,
                              hipStream_t stream) {
  const float* x     = (const float*)d_in[0];
  const float* W1    = (const float*)d_in[1];
  const float* b1    = (const float*)d_in[2];
  const float* Wmeta = (const float*)d_in[3];
  const float* bmeta = (const float*)d_in[4];
  const float* W2    = (const float*)d_in[5];
  const float* b2    = (const float*)d_in[6];
  const float* W3    = (const float*)d_in[7];
  const float* b3    = (const float*)d_in[8];
  float* out = (float*)d_out;

  char* ws = (char*)d_ws;
  unsigned short* hbuf  = (unsigned short*)ws;                              // 128 MiB
  unsigned short* W2bf  = (unsigned short*)(ws + (size_t)NROWS * HD * 2);   // 2 MiB
  float* partial = (float*)(ws + (size_t)NROWS * HD * 2 + (size_t)HD * HD * 2);  // 2 MiB

  hipFuncSetAttribute((const void*)k_gemm, hipFuncAttributeMaxDynamicSharedMemorySize, 131072);

  k_w2bf<<<512, 256, 0, stream>>>(W2, W2bf);
  k_layer1<<<512, 512, 0, stream>>>(x, W1, b1, Wmeta, bmeta, hbuf);
  k_gemm<<<1024, 512, 131072, stream>>>(hbuf, W2bf, b2, W3, partial);
  k_reduce<<<512, 256, 0, stream>>>(partial, b3, out);
}

// Round 5
// 208.733 us; speedup vs baseline: 1.2199x; 1.1587x over previous
//
#include <hip/hip_runtime.h>
#include <stdint.h>

#define NROWS 65536
#define HD 1024

typedef __attribute__((ext_vector_type(8))) short bf16x8;   // 8 bf16 in 4 VGPRs
typedef __attribute__((ext_vector_type(16))) float f32x16;  // MFMA 32x32 accumulator

typedef __attribute__((address_space(1))) const unsigned int* gas_ptr;
typedef __attribute__((address_space(3))) unsigned int* las_ptr;

__device__ __forceinline__ unsigned short f2bf(float f) {
  union { float f; uint32_t u; } v; v.f = f;
  uint32_t u = v.u;
  return (unsigned short)((u + 0x7fffu + ((u >> 16) & 1u)) >> 16);  // RNE
}

__device__ __forceinline__ void gl16(const void* g, void* l) {
  __builtin_amdgcn_global_load_lds((gas_ptr)g, (las_ptr)l, 16, 0, 0);
}

// ---------------- prep: W2 fp32 -> bf16, swizzled granules (unchanged layout) ----------------
// W2bf[c][k]; 16B granule g stored at (g&~3) | ((g&3) ^ ((c>>1)&3)).
__global__ void k_w2bf(const float* __restrict__ W2, unsigned short* __restrict__ W2bf) {
  int i = blockIdx.x * 256 + threadIdx.x;   // 131072 threads, 1 granule each
  int c = i >> 7, g = i & 127;
  const float4* s4 = (const float4*)(W2 + (size_t)c * HD + g * 8);
  float4 a = s4[0], b = s4[1];
  uint4 pk;
  pk.x = (uint32_t)f2bf(a.x) | ((uint32_t)f2bf(a.y) << 16);
  pk.y = (uint32_t)f2bf(a.z) | ((uint32_t)f2bf(a.w) << 16);
  pk.z = (uint32_t)f2bf(b.x) | ((uint32_t)f2bf(b.y) << 16);
  pk.w = (uint32_t)f2bf(b.z) | ((uint32_t)f2bf(b.w) << 16);
  int gs = (g & 124) | ((g & 3) ^ ((c >> 1) & 3));
  *(uint4*)(W2bf + (size_t)c * HD + gs * 8) = pk;
}

// ---------------- layer 1 (unchanged): h bf16 [65536][1024], same granule swizzle ----------------
__global__ __launch_bounds__(512) void k_layer1(
    const float* __restrict__ x, const float* __restrict__ W1,
    const float* __restrict__ b1, const float* __restrict__ Wmeta,
    const float* __restrict__ bmeta, unsigned short* __restrict__ h) {
  __shared__ float xs[128 * 12];
  int r0 = blockIdx.x * 128;
  int t = threadIdx.x;
  int j0 = t * 2;
  float w1a = W1[j0], w1b = W1[j0 + 1];
  float b1a = b1[j0], b1b = b1[j0 + 1];
  float wma[10], wmb[10], bma[10], bmb[10];
#pragma unroll
  for (int e = 0; e < 10; e++) {
    float2 wmv = *(const float2*)(Wmeta + e * HD + j0);
    float2 bmv = *(const float2*)(bmeta + e * HD + j0);
    wma[e] = wmv.x; wmb[e] = wmv.y; bma[e] = bmv.x; bmb[e] = bmv.y;
  }
  for (int i = t; i < 128 * 12; i += 512) xs[i] = x[(size_t)r0 * 12 + i];
  __syncthreads();
  int g = j0 >> 3;
  for (int r = 0; r < 128; r++) {
    const float* xr = xs + r * 12;
    float delta = xr[10], phi = xr[11];
    float s1a = 0.f, s1b = 0.f, s2a = 0.f, s2b = 0.f;
#pragma unroll
    for (int e = 0; e < 10; e++) {
      float oh = xr[e];
      s1a = fmaf(oh, wma[e], s1a);
      s1b = fmaf(oh, wmb[e], s1b);
      s2a = fmaf(oh, bma[e], s2a);
      s2b = fmaf(oh, bmb[e], s2b);
    }
    float pa = fmaf(delta, w1a, b1a) + fmaf(phi, s1a, s2a);
    float pb = fmaf(delta, w1b, b1b) + fmaf(phi, s1b, s2b);
    pa = fmaxf(pa, 0.f); pb = fmaxf(pb, 0.f);
    uint32_t pk = (uint32_t)f2bf(pa) | ((uint32_t)f2bf(pb) << 16);
    int rr = r0 + r;
    int gs = (g & 124) | ((g & 3) ^ ((rr >> 1) & 3));
    *(uint32_t*)(h + (size_t)rr * HD + gs * 8 + (j0 & 7)) = pk;
  }
}

// ---------------- layers 2+3: m97-structure 128x128 tile, 3 blocks/CU ----------------
// grid 4096 blocks (XCD-swizzled) = 512 rt x 8 ct; 256 threads = 4 waves (2x2),
// wave tile 64x64 = 2x2 of 32x32x16 bf16 MFMA (acc = 64 VGPR).
// LDS: single buffer, A[2 panels][128][64B] + B same = 32 KiB (+2 KiB epilogue pad).
// Per K-tile: {8 gl_lds | __syncthreads | 16 ds_read_b128 + 16 MFMA | __syncthreads}.
// Cross-block overlap at 3 blocks/CU hides the barrier drains (m97 mechanism).
__global__ __launch_bounds__(256, 3) void k_gemm(
    const unsigned short* __restrict__ h, const unsigned short* __restrict__ W2bf,
    const float* __restrict__ b2, const float* __restrict__ W3,
    float* __restrict__ partial) {
  __shared__ char lds[34816];   // 32 KiB tiles; epilogue uses 33792 B (padded lines)
  int tid = threadIdx.x;
  // XCD swizzle: 4096 blocks = 8 XCDs x 512; XCD k gets contiguous logical range.
  int b = (int)blockIdx.x;
  int bx = ((b & 7) << 9) | (b >> 3);
  int rt = bx >> 3, ct = bx & 7;   // 8 consecutive bx share rt -> A-panel L2 reuse
  size_t r0 = (size_t)rt * 128;
  int c0 = ct * 128;
  int w = tid >> 6, lane = tid & 63;
  int wm = w >> 1, wn = w & 1;
  int l31 = lane & 31, hi = lane >> 5;
  int sw = (l31 >> 1) & 3;   // granule swizzle key (row base multiple of 32)

  f32x16 acc[2][2];
#pragma unroll
  for (int rb = 0; rb < 2; rb++)
#pragma unroll
    for (int cb = 0; cb < 2; cb++)
#pragma unroll
      for (int i = 0; i < 16; i++) acc[rb][cb][i] = 0.f;

  // frag byte offsets within a panel (row*64 + slot*16), rows 0..127
  int arow0 = (wm * 64 + 0  + l31) * 64;
  int arow1 = (wm * 64 + 32 + l31) * 64;
  int brow0 = (wn * 64 + 0  + l31) * 64;
  int brow1 = (wn * 64 + 32 + l31) * 64;

  for (int T = 0; T < 16; T++) {
    // stage tile T: A panels at 0/8192, B panels at 16384/24576; dest linear in s.
#pragma unroll
    for (int q = 0; q < 2; q++) {
      int s = tid + 256 * q;            // 0..511
      int row = s >> 2, g4 = s & 3;
      const unsigned short* hsrc = h    + (r0 + row) * (size_t)HD + T * 64 + g4 * 8;
      const unsigned short* wsrc = W2bf + (size_t)(c0 + row) * HD + T * 64 + g4 * 8;
      gl16(hsrc,      lds +         (size_t)s * 16);
      gl16(hsrc + 32, lds +  8192 + (size_t)s * 16);
      gl16(wsrc,      lds + 16384 + (size_t)s * 16);
      gl16(wsrc + 32, lds + 24576 + (size_t)s * 16);
    }
    __syncthreads();   // drains vmcnt: tile T landed; prior reads done before overwrite
#pragma unroll
    for (int p = 0; p < 2; p++) {
      const char* lA = lds + p * 8192;
      const char* lB = lds + 16384 + p * 8192;
#pragma unroll
      for (int kl = 0; kl < 2; kl++) {
        int slot = ((kl * 2 + hi) ^ sw) << 4;
        bf16x8 a0 = *(const bf16x8*)(lA + arow0 + slot);
        bf16x8 a1 = *(const bf16x8*)(lA + arow1 + slot);
        bf16x8 b0 = *(const bf16x8*)(lB + brow0 + slot);
        bf16x8 b1 = *(const bf16x8*)(lB + brow1 + slot);
        acc[0][0] = __builtin_amdgcn_mfma_f32_32x32x16_bf16(a0, b0, acc[0][0], 0, 0, 0);
        acc[0][1] = __builtin_amdgcn_mfma_f32_32x32x16_bf16(a0, b1, acc[0][1], 0, 0, 0);
        acc[1][0] = __builtin_amdgcn_mfma_f32_32x32x16_bf16(a1, b0, acc[1][0], 0, 0, 0);
        acc[1][1] = __builtin_amdgcn_mfma_f32_32x32x16_bf16(a1, b1, acc[1][1], 0, 0, 0);
      }
    }
    __syncthreads();
  }

  // ---- epilogue: v = relu(acc+b2); o = v x W3^T; LDS transpose-reduce (no shfl storm) ----
  float b2c[2], w30[2], w31[2];
#pragma unroll
  for (int cb = 0; cb < 2; cb++) {
    int c = c0 + wn * 64 + cb * 32 + l31;
    b2c[cb] = b2[c];
    w30[cb] = W3[c];
    w31[cb] = W3[HD + c];
  }
  // padded layout: line = (wm*32+rowf)*2 + wn in [0,128); float2 slot = line*33 + l31
  float2* sE = (float2*)lds;
#pragma unroll
  for (int rb = 0; rb < 2; rb++) {
    __syncthreads();
#pragma unroll
    for (int reg = 0; reg < 16; reg++) {
      float v0 = fmaxf(acc[rb][0][reg] + b2c[0], 0.f);
      float v1 = fmaxf(acc[rb][1][reg] + b2c[1], 0.f);
      float2 o;
      o.x = v0 * w30[0] + v1 * w30[1];
      o.y = v0 * w31[0] + v1 * w31[1];
      int rowf = (reg & 3) + 8 * (reg >> 2) + 4 * hi;   // verified C/D row map
      int line = (wm * 32 + rowf) * 2 + wn;
      sE[line * 33 + l31] = o;
    }
    __syncthreads();
    // reduce: 128 targets (bi 2 x rowf 32 x d 2), 2 threads each (half = wn index)
    int half = tid & 1, tgt = tid >> 1;
    int d = tgt & 1, rowf_t = (tgt >> 1) & 31, bi = tgt >> 6;
    int line0 = (bi * 32 + rowf_t) * 2 + half;
    const float* sf = (const float*)lds;
    float s = 0.f;
#pragma unroll
    for (int j = 0; j < 32; j++) s += sf[(line0 * 33 + j) * 2 + d];
    s += __shfl_xor(s, 1);
    if (half == 0) {
      int row = bi * 64 + rb * 32 + rowf_t;
      partial[(size_t)ct * (NROWS * 2) + (r0 + row) * 2 + d] = s;
    }
  }
}

// ---------------- final: out = b3 + sum over 8 col-tile partials ----------------
__global__ void k_reduce(const float* __restrict__ partial, const float* __restrict__ b3,
                         float* __restrict__ out) {
  int i = blockIdx.x * 256 + threadIdx.x;  // 131072
  float s = b3[i & 1];
#pragma unroll
  for (int ctt = 0; ctt < 8; ctt++) s += partial[(size_t)ctt * 131072 + i];
  out[i] = s;
}

extern "C" void kernel_launch(void* const* d_in, const int* in_sizes, int n_in,
                              void* d_out, int out_size, void* d_ws, size_t ws_size,
                              hipStream_t stream) {
  const float* x     = (const float*)d_in[0];
  const float* W1    = (const float*)d_in[1];
  const float* b1    = (const float*)d_in[2];
  const float* Wmeta = (const float*)d_in[3];
  const float* bmeta = (const float*)d_in[4];
  const float* W2    = (const float*)d_in[5];
  const float* b2    = (const float*)d_in[6];
  const float* W3    = (const float*)d_in[7];
  const float* b3    = (const float*)d_in[8];
  float* out = (float*)d_out;

  char* ws = (char*)d_ws;
  unsigned short* hbuf  = (unsigned short*)ws;                              // 128 MiB
  unsigned short* W2bf  = (unsigned short*)(ws + (size_t)NROWS * HD * 2);   // 2 MiB
  float* partial = (float*)(ws + (size_t)NROWS * HD * 2 + (size_t)HD * HD * 2);  // 4 MiB (8 slices)

  k_w2bf<<<512, 256, 0, stream>>>(W2, W2bf);
  k_layer1<<<512, 512, 0, stream>>>(x, W1, b1, Wmeta, bmeta, hbuf);
  k_gemm<<<4096, 256, 0, stream>>>(hbuf, W2bf, b2, W3, partial);
  k_reduce<<<512, 256, 0, stream>>>(partial, b3, out);
}